// Round 1
// baseline (117.107 us; speedup 1.0000x reference)
//
#include <hip/hip_runtime.h>

// MultiQueryAttention — algebraically collapsed.
// Reference einsum 'bqnk,bvd->bqnd' sums k and v independently; softmax
// weights sum to 1, so output[b,q,n,d] = (sum_s v[b,s,d]) for all q,n.
// Final = tile(vsum,8) @ Wo + bo, broadcast over all s.
//
// Pipeline (all deterministic two-phase reductions, no atomics):
//   A: partial xsum over seq        (128 blocks x 512)
//   B: reduce -> xsum[2][512]       (1 block x 1024)
//   C: partial vsum = xsum @ Wv     (16 blocks x 512)
//   D: reduce + SEQ*bv -> vsum      (1 block x 1024)
//   E: partial outrow = vsum @ Wo'  (64 blocks x 512)  Wo' = fold 8 tiles
//   F: reduce + bo -> outrow        (1 block x 1024)
//   G: broadcast outrow -> out      (1024 blocks x 512, float4 stores)

#define DM   512
#define SEQL 2048

// ws layout (float offsets)
static constexpr size_t OFF_P1 = 0;       // [2][64][512] partial xsum   (65536)
static constexpr size_t OFF_XS = 65536;   // [2][512]                    (1024)
static constexpr size_t OFF_PV = 66560;   // [16][2][512] partial vsum   (16384)
static constexpr size_t OFF_VS = 82944;   // [2][512]                    (1024)
static constexpr size_t OFF_PO = 83968;   // [64][2][512] partial outrow (65536)
static constexpr size_t OFF_OR = 149504;  // [2][512]                    (1024)

__global__ void k_xsum_partial(const float* __restrict__ x, float* __restrict__ P1) {
    // blockIdx.x = b*64 + chunk; each block sums 32 seq rows for all 512 d
    const int c32 = blockIdx.x;            // combined (b, chunk)
    const int d = threadIdx.x;
    const float* xp = x + (size_t)c32 * 32 * DM + d;
    float acc = 0.f;
#pragma unroll
    for (int i = 0; i < 32; ++i) acc += xp[(size_t)i * DM];
    P1[(size_t)c32 * DM + d] = acc;
}

__global__ void k_xsum_reduce(const float* __restrict__ P1, float* __restrict__ XS) {
    const int t = threadIdx.x;             // t = b*512 + d
    const int b = t >> 9, d = t & 511;
    float acc = 0.f;
#pragma unroll
    for (int c = 0; c < 64; ++c) acc += P1[(size_t)((b << 6) + c) * DM + d];
    XS[t] = acc;
}

__global__ void k_vsum_partial(const float* __restrict__ Wv, const float* __restrict__ XS,
                               float* __restrict__ PV) {
    const int chunk = blockIdx.x;          // dd range [chunk*32, chunk*32+32)
    const int d = threadIdx.x;
    float a0 = 0.f, a1 = 0.f;
#pragma unroll
    for (int i = 0; i < 32; ++i) {
        const int dd = chunk * 32 + i;
        const float w = Wv[(size_t)dd * DM + d];
        a0 += XS[dd] * w;
        a1 += XS[DM + dd] * w;
    }
    PV[(size_t)(chunk * 2 + 0) * DM + d] = a0;
    PV[(size_t)(chunk * 2 + 1) * DM + d] = a1;
}

__global__ void k_vsum_reduce(const float* __restrict__ PV, const float* __restrict__ bv,
                              float* __restrict__ VS) {
    const int t = threadIdx.x;
    const int b = t >> 9, d = t & 511;
    float acc = (float)SEQL * bv[d];
#pragma unroll
    for (int c = 0; c < 16; ++c) acc += PV[(size_t)(c * 2 + b) * DM + d];
    VS[t] = acc;
}

__global__ void k_outrow_partial(const float* __restrict__ Wo, const float* __restrict__ VS,
                                 float* __restrict__ PO) {
    const int chunk = blockIdx.x;          // r range [chunk*64, chunk*64+64), r in [0,4096)
    const int dout = threadIdx.x;
    float a0 = 0.f, a1 = 0.f;
#pragma unroll
    for (int i = 0; i < 64; ++i) {
        const int r = chunk * 64 + i;
        const int dd = r & 511;            // fold 8 tiles of Wo rows onto vsum
        const float w = Wo[(size_t)r * DM + dout];
        a0 += VS[dd] * w;
        a1 += VS[DM + dd] * w;
    }
    PO[(size_t)(chunk * 2 + 0) * DM + dout] = a0;
    PO[(size_t)(chunk * 2 + 1) * DM + dout] = a1;
}

__global__ void k_outrow_reduce(const float* __restrict__ PO, const float* __restrict__ bo,
                                float* __restrict__ OR_) {
    const int t = threadIdx.x;
    const int b = t >> 9, d = t & 511;
    float acc = bo[d];
#pragma unroll
    for (int c = 0; c < 64; ++c) acc += PO[(size_t)(c * 2 + b) * DM + d];
    OR_[t] = acc;
}

__global__ void k_broadcast(const float* __restrict__ OR_, float* __restrict__ out4) {
    // one float4 per thread; 2*2048*512 floats = 524288 float4
    const int idx = blockIdx.x * blockDim.x + threadIdx.x;
    const int col4 = idx & 127;            // 128 float4 per 512-wide row
    const int row  = idx >> 7;             // b*2048 + s
    const int b    = row >> 11;
    const float4 v = *reinterpret_cast<const float4*>(OR_ + ((size_t)(b << 9) + (col4 << 2)));
    reinterpret_cast<float4*>(out4)[idx] = v;
}

extern "C" void kernel_launch(void* const* d_in, const int* in_sizes, int n_in,
                              void* d_out, int out_size, void* d_ws, size_t ws_size,
                              hipStream_t stream) {
    const float* x  = (const float*)d_in[0];
    // d_in[1..4] = Wq, bq, Wk, bk — provably unused (softmax weights sum to 1)
    const float* Wv = (const float*)d_in[5];
    const float* bv = (const float*)d_in[6];
    const float* Wo = (const float*)d_in[7];
    const float* bo = (const float*)d_in[8];
    float* out = (float*)d_out;
    float* ws  = (float*)d_ws;

    float* P1 = ws + OFF_P1;
    float* XS = ws + OFF_XS;
    float* PV = ws + OFF_PV;
    float* VS = ws + OFF_VS;
    float* PO = ws + OFF_PO;
    float* OR_ = ws + OFF_OR;

    hipLaunchKernelGGL(k_xsum_partial,  dim3(128),  dim3(512),  0, stream, x, P1);
    hipLaunchKernelGGL(k_xsum_reduce,   dim3(1),    dim3(1024), 0, stream, P1, XS);
    hipLaunchKernelGGL(k_vsum_partial,  dim3(16),   dim3(512),  0, stream, Wv, XS, PV);
    hipLaunchKernelGGL(k_vsum_reduce,   dim3(1),    dim3(1024), 0, stream, PV, bv, VS);
    hipLaunchKernelGGL(k_outrow_partial,dim3(64),   dim3(512),  0, stream, Wo, VS, PO);
    hipLaunchKernelGGL(k_outrow_reduce, dim3(1),    dim3(1024), 0, stream, PO, bo, OR_);
    hipLaunchKernelGGL(k_broadcast,     dim3(1024), dim3(512),  0, stream, OR_, out);
}

// Round 2
// 96.322 us; speedup vs baseline: 1.2158x; 1.2158x over previous
//
#include <hip/hip_runtime.h>

// MultiQueryAttention — algebraically collapsed (verified R1, absmax 0.0).
// Reference einsum 'bqnk,bvd->bqnd' sums k and v independently; softmax
// weights sum to 1, so output[b,q,n,d] = vsum[b,d] for all q,n where
// vsum = (sum_s x) @ Wv + SEQ*bv.  Final = tile(vsum,8) @ Wo + bo.
//
// R2: 5 stream nodes, no single-block stages, split-K via HW float atomics.
//   0: hipMemsetAsync zero XS/VS/OR (12 KB)
//   1: k_xsum    128 blocks  — xsum partials, atomicAdd into XS   (reads 8 MB)
//   2: k_vsum     32 blocks  — XS @ Wv (+SEQ*bv), atomic into VS  (reads 1 MB)
//   3: k_outrow  128 blocks  — tile-fold VS @ Wo (+bo), atomic OR (reads 8 MB)
//   4: k_broadcast 2048x256  — float4 broadcast of OR over seq    (writes 8 MB)

#define DM   512
#define SEQL 2048

// ws layout (float offsets) — one contiguous accumulator region, memset once
static constexpr size_t OFF_XS = 0;      // [2][512] xsum
static constexpr size_t OFF_VS = 1024;   // [2][512] vsum
static constexpr size_t OFF_OR = 2048;   // [2][512] outrow
static constexpr size_t ACC_BYTES = 3072 * sizeof(float);

__global__ void k_xsum(const float* __restrict__ x, float* __restrict__ XS) {
    // blockIdx.x = b*64 + chunk; each block sums 32 seq rows for all 512 d
    const int c32 = blockIdx.x;
    const int b   = c32 >> 6;
    const int d   = threadIdx.x;
    const float* xp = x + (size_t)c32 * 32 * DM + d;
    float acc = 0.f;
#pragma unroll
    for (int i = 0; i < 32; ++i) acc += xp[(size_t)i * DM];
    unsafeAtomicAdd(&XS[(b << 9) + d], acc);
}

__global__ void k_vsum(const float* __restrict__ Wv, const float* __restrict__ bv,
                       const float* __restrict__ XS, float* __restrict__ VS) {
    // blockIdx.x in [0,32): dd range [chunk*16, chunk*16+16)
    const int chunk = blockIdx.x;
    const int d = threadIdx.x;
    float a0 = 0.f, a1 = 0.f;
#pragma unroll
    for (int i = 0; i < 16; ++i) {
        const int dd = (chunk << 4) + i;
        const float w = Wv[(size_t)dd * DM + d];
        a0 += XS[dd] * w;
        a1 += XS[DM + dd] * w;
    }
    if (chunk == 0) {                      // fold bias exactly once
        const float bb = (float)SEQL * bv[d];
        a0 += bb; a1 += bb;
    }
    unsafeAtomicAdd(&VS[d], a0);
    unsafeAtomicAdd(&VS[DM + d], a1);
}

__global__ void k_outrow(const float* __restrict__ Wo, const float* __restrict__ bo,
                         const float* __restrict__ VS, float* __restrict__ OR_) {
    // blockIdx.x in [0,128): r range [blk*32, blk*32+32), r in [0,4096)
    const int blk = blockIdx.x;
    const int dout = threadIdx.x;
    float a0 = 0.f, a1 = 0.f;
#pragma unroll
    for (int i = 0; i < 32; ++i) {
        const int r  = (blk << 5) + i;
        const int dd = r & 511;            // fold 8 row-tiles of Wo onto vsum
        const float w = Wo[(size_t)r * DM + dout];
        a0 += VS[dd] * w;
        a1 += VS[DM + dd] * w;
    }
    if (blk == 0) {                        // fold bias exactly once
        const float bb = bo[dout];
        a0 += bb; a1 += bb;
    }
    unsafeAtomicAdd(&OR_[dout], a0);
    unsafeAtomicAdd(&OR_[DM + dout], a1);
}

__global__ void k_broadcast(const float* __restrict__ OR_, float4* __restrict__ out4) {
    // one float4 per thread; 2*2048*512 floats = 524288 float4 = 2048 blk x 256
    const int idx = blockIdx.x * blockDim.x + threadIdx.x;
    const int col4 = idx & 127;            // 128 float4 per 512-wide row
    const int b    = idx >> 18;            // row = idx>>7, b = row>>11
    out4[idx] = *reinterpret_cast<const float4*>(OR_ + ((size_t)(b << 9) + (col4 << 2)));
}

extern "C" void kernel_launch(void* const* d_in, const int* in_sizes, int n_in,
                              void* d_out, int out_size, void* d_ws, size_t ws_size,
                              hipStream_t stream) {
    const float* x  = (const float*)d_in[0];
    // d_in[1..4] = Wq, bq, Wk, bk — provably unused (softmax weights sum to 1)
    const float* Wv = (const float*)d_in[5];
    const float* bv = (const float*)d_in[6];
    const float* Wo = (const float*)d_in[7];
    const float* bo = (const float*)d_in[8];
    float* ws  = (float*)d_ws;

    float* XS  = ws + OFF_XS;
    float* VS  = ws + OFF_VS;
    float* OR_ = ws + OFF_OR;

    hipMemsetAsync(ws, 0, ACC_BYTES, stream);
    hipLaunchKernelGGL(k_xsum,      dim3(128),  dim3(512), 0, stream, x, XS);
    hipLaunchKernelGGL(k_vsum,      dim3(32),   dim3(512), 0, stream, Wv, bv, XS, VS);
    hipLaunchKernelGGL(k_outrow,    dim3(128),  dim3(512), 0, stream, Wo, bo, VS, OR_);
    hipLaunchKernelGGL(k_broadcast, dim3(2048), dim3(256), 0, stream, OR_, (float4*)d_out);
}